// Round 6
// baseline (312.018 us; speedup 1.0000x reference)
//
#include <hip/hip_runtime.h>

// Round 13: drop the 128 MB fp16 quad table entirely; gather fp32 directly
// from vol. Rationale: per-iteration working set was table 128 + vol 64 +
// xyz 105 = ~300 MB > 256 MB L3 -> steady-state FETCH pinned at 147 MB and
// build_quad re-ran every iteration (~28 us of traffic). Without the table
// the working set (vol 64 + xyz 105) fits L3 -> steady-state HBM fetch
// should collapse; 8 independent 4B gathers/lane also give 4x the MLP of
// the 2 table gathers (the latency hiding R9-R12 failed to buy). xyz loads
// are now cacheable (nontemporal removed - we WANT L3 retention).
// Keeps: spatial sort, setup hoisted into scatter (pre[]), separable masked
// weights, one-shot dispatch + XCD swizzle, 1 sample per wave.

#define VOL_N 256
#define S_PSF 64
#define NBUCKET 4096   // 16x16x16 cells of 16^3 voxels

__device__ __forceinline__ int bucket_of(const float* __restrict__ sg, int n) {
    int cx = min(max((int)sg[n * 3 + 0], 0), VOL_N - 1) >> 4;
    int cy = min(max((int)sg[n * 3 + 1], 0), VOL_N - 1) >> 4;
    int cz = min(max((int)sg[n * 3 + 2], 0), VOL_N - 1) >> 4;
    int m = 0;
    #pragma unroll
    for (int b = 0; b < 4; b++) {
        m |= (((cx >> b) & 1) << (3 * b))
           | (((cy >> b) & 1) << (3 * b + 1))
           | (((cz >> b) & 1) << (3 * b + 2));
    }
    return m;
}

__global__ void zero_hist_kernel(int* __restrict__ ws) {
    int i = blockIdx.x * blockDim.x + threadIdx.x;
    if (i < NBUCKET) ws[i] = 0;
}

__global__ void hist_kernel(const float* __restrict__ sg, int* __restrict__ ws, int N) {
    int n = blockIdx.x * blockDim.x + threadIdx.x;
    if (n >= N) return;
    atomicAdd(&ws[bucket_of(sg, n)], 1);
}

__global__ __launch_bounds__(1024) void scan_kernel(int* __restrict__ ws) {
    __shared__ int tmp[1024];
    const int t = threadIdx.x;
    int h0 = ws[t * 4 + 0], h1 = ws[t * 4 + 1], h2 = ws[t * 4 + 2], h3 = ws[t * 4 + 3];
    int s = h0 + h1 + h2 + h3;
    tmp[t] = s;
    __syncthreads();
    for (int off = 1; off < 1024; off <<= 1) {
        int v = (t >= off) ? tmp[t - off] : 0;
        __syncthreads();
        tmp[t] += v;
        __syncthreads();
    }
    int excl = tmp[t] - s;
    ws[NBUCKET + t * 4 + 0] = excl;
    ws[NBUCKET + t * 4 + 1] = excl + h0;
    ws[NBUCKET + t * 4 + 2] = excl + h0 + h1;
    ws[NBUCKET + t * 4 + 3] = excl + h0 + h1 + h2;
}

// Scatter + fused per-sample setup: rotated center (pre-scaled to voxel-index
// space) and half extents written at the SORTED position.
__global__ void scatter_kernel(const float* __restrict__ sg,
                               const float* __restrict__ ax,
                               const float* __restrict__ bound,
                               int* __restrict__ ws,
                               float* __restrict__ pre, int N) {
    int n = blockIdx.x * blockDim.x + threadIdx.x;
    if (n >= N) return;
    int b = bucket_of(sg, n);
    int pos = atomicAdd(&ws[NBUCKET + b], 1);
    ws[2 * NBUCKET + pos] = n;

    const float vx = ax[n * 6 + 0], vy = ax[n * 6 + 1], vz = ax[n * 6 + 2];
    const float tx = ax[n * 6 + 3], ty = ax[n * 6 + 4], tz = ax[n * 6 + 5];

    const float theta = sqrtf(vx * vx + vy * vy + vz * vz);
    const float kinv = 1.0f / fmaxf(theta, 1e-12f);
    const float kx = vx * kinv, ky = vy * kinv, kz = vz * kinv;
    const float ct = __cosf(theta), st = __sinf(theta);
    const float oc = 1.0f - ct;

    const float r00 = 1.0f + oc * (-(ky * ky + kz * kz));
    const float r01 = -st * kz + oc * kx * ky;
    const float r02 =  st * ky + oc * kx * kz;
    const float r10 =  st * kz + oc * kx * ky;
    const float r11 = 1.0f + oc * (-(kx * kx + kz * kz));
    const float r12 = -st * kx + oc * ky * kz;
    const float r20 = -st * ky + oc * kx * kz;
    const float r21 =  st * kx + oc * ky * kz;
    const float r22 = 1.0f + oc * (-(kx * kx + ky * ky));

    const float px = sg[n * 3 + 0] + tx;
    const float py = sg[n * 3 + 1] + ty;
    const float pz = sg[n * 3 + 2] + tz;

    const float cx = r00 * px + r01 * py + r02 * pz;
    const float cy = r10 * px + r11 * py + r12 * pz;
    const float cz = r20 * px + r21 * py + r22 * pz;

    const float hx = (bound[n * 6 + 3] - bound[n * 6 + 0]) * 0.5f;
    const float hy = (bound[n * 6 + 4] - bound[n * 6 + 1]) * 0.5f;
    const float hz = (bound[n * 6 + 5] - bound[n * 6 + 2]) * 0.5f;

    const float scale = (float)VOL_N / (float)(VOL_N - 1);
    float4 A = make_float4(cx * scale - 0.5f, cy * scale - 0.5f,
                           cz * scale - 0.5f, hx);
    float4 B = make_float4(hy, hz, 0.0f, 0.0f);
    *(float4*)(pre + (size_t)pos * 8)     = A;
    *(float4*)(pre + (size_t)pos * 8 + 4) = B;
}

// Direct-vol sampler: 1 sample per wave, 8 independent fp32 gathers per lane
// (max MLP), separable masked weights handle all boundary cases.
__global__ __launch_bounds__(256, 4) void psf_sample_vol_kernel(
    const float* __restrict__ vol,        // [256][256][256] (z,y,x) fp32
    const float* __restrict__ invcov,     // [3][3]
    const float* __restrict__ xyz_psf,    // [N][64][3]
    const int* __restrict__ perm,         // sorted pos -> n
    const float* __restrict__ pre,        // [N][8] precomputed setup (sorted)
    float* __restrict__ out,              // [N]
    int N)
{
    const int lane = threadIdx.x & 63;

    // XCD-contiguous swizzle so each XCD sweeps a contiguous sorted range
    int bid = blockIdx.x;
    const int nb = gridDim.x;
    if ((nb & 7) == 0) bid = (bid & 7) * (nb >> 3) + (bid >> 3);

    const int i = bid * (int)(blockDim.x >> 6) + (int)(threadIdx.x >> 6);
    if (i >= N) return;
    const int n = __builtin_amdgcn_readfirstlane(perm[i]);

    const float4 A = *(const float4*)(pre + (size_t)i * 8);
    const float4 B = *(const float4*)(pre + (size_t)i * 8 + 4);
    const float icx = A.x, icy = A.y, icz = A.z;
    const float hx = A.w, hy = B.x, hz = B.y;

    const float m00 = invcov[0], m01 = invcov[1], m02 = invcov[2];
    const float m10 = invcov[3], m11 = invcov[4], m12 = invcov[5];
    const float m20 = invcov[6], m21 = invcov[7], m22 = invcov[8];
    const float scale = (float)VOL_N / (float)(VOL_N - 1);

    // per-lane PSF point (cacheable: we want xyz L3-resident across iters)
    const int pbase = (n * S_PSF + lane) * 3;
    const float gx = xyz_psf[pbase + 0];
    const float gy = xyz_psf[pbase + 1];
    const float gz = xyz_psf[pbase + 2];
    const float ox = gx * hx, oy = gy * hy, oz = gz * hz;

    const float ix = fmaf(ox, scale, icx);
    const float iy = fmaf(oy, scale, icy);
    const float iz = fmaf(oz, scale, icz);

    const float x0f = floorf(ix), y0f = floorf(iy), z0f = floorf(iz);
    const float fx = ix - x0f, fy = iy - y0f, fz = iz - z0f;
    const int x0 = (int)x0f, y0 = (int)y0f, z0 = (int)z0f;

    // validity folded into separable axis weights (corner mask == product)
    const float wx0 = ((unsigned)x0       < (unsigned)VOL_N) ? (1.0f - fx) : 0.0f;
    const float wx1 = ((unsigned)(x0 + 1) < (unsigned)VOL_N) ? fx          : 0.0f;
    const float wy0 = ((unsigned)y0       < (unsigned)VOL_N) ? (1.0f - fy) : 0.0f;
    const float wy1 = ((unsigned)(y0 + 1) < (unsigned)VOL_N) ? fy          : 0.0f;
    const float wz0 = ((unsigned)z0       < (unsigned)VOL_N) ? (1.0f - fz) : 0.0f;
    const float wz1 = ((unsigned)(z0 + 1) < (unsigned)VOL_N) ? fz          : 0.0f;

    const int xc0 = min(max(x0, 0), VOL_N - 1);
    const int xc1 = min(max(x0 + 1, 0), VOL_N - 1);
    const int yc0 = min(max(y0, 0), VOL_N - 1);
    const int yc1 = min(max(y0 + 1, 0), VOL_N - 1);
    const int zc0 = min(max(z0, 0), VOL_N - 1);
    const int zc1 = min(max(z0 + 1, 0), VOL_N - 1);
    const int zo0 = zc0 << 16, zo1 = zc1 << 16;
    const int yo0 = yc0 << 8, yo1 = yc1 << 8;

    // 8 independent gathers - all issued before first use (max MLP)
    const float v000 = vol[zo0 + yo0 + xc0];
    const float v001 = vol[zo0 + yo0 + xc1];
    const float v010 = vol[zo0 + yo1 + xc0];
    const float v011 = vol[zo0 + yo1 + xc1];
    const float v100 = vol[zo1 + yo0 + xc0];
    const float v101 = vol[zo1 + yo0 + xc1];
    const float v110 = vol[zo1 + yo1 + xc0];
    const float v111 = vol[zo1 + yo1 + xc1];

    // pure-FMA separable trilinear (masked weights zero invalid corners)
    const float r0 = fmaf(v001, wx1, v000 * wx0);
    const float r1 = fmaf(v011, wx1, v010 * wx0);
    const float r2 = fmaf(v101, wx1, v100 * wx0);
    const float r3 = fmaf(v111, wx1, v110 * wx0);
    const float s0 = fmaf(r1, wy1, r0 * wy0);
    const float s1 = fmaf(r3, wy1, r2 * wy0);
    const float acc = fmaf(s1, wz1, s0 * wz0);

    const float qx = fmaf(m00, ox, fmaf(m01, oy, m02 * oz));
    const float qy = fmaf(m10, ox, fmaf(m11, oy, m12 * oz));
    const float qz = fmaf(m20, ox, fmaf(m21, oy, m22 * oz));
    const float q = fmaf(ox, qx, fmaf(oy, qy, oz * qz));
    const float w = __expf(-0.5f * q);

    float num = acc * w;
    float den = w;
    #pragma unroll
    for (int m = 32; m >= 1; m >>= 1) {
        num += __shfl_xor(num, m, 64);
        den += __shfl_xor(den, m, 64);
    }
    if (lane == 0) out[n] = num / den;
}

// Fallback (no workspace): one sample per wave, setup in-kernel.
__global__ __launch_bounds__(256, 4) void psf_sample_plain_kernel(
    const float* __restrict__ vol,
    const float* __restrict__ sampleGrid,
    const float* __restrict__ ax,
    const float* __restrict__ bound,
    const float* __restrict__ invcov,
    const float* __restrict__ xyz_psf,
    float* __restrict__ out,
    int N)
{
    const int lane = threadIdx.x & 63;
    const int i = blockIdx.x * (blockDim.x >> 6) + (threadIdx.x >> 6);
    if (i >= N) return;
    const int n = __builtin_amdgcn_readfirstlane(i);

    const float vx = ax[n * 6 + 0], vy = ax[n * 6 + 1], vz = ax[n * 6 + 2];
    const float tx = ax[n * 6 + 3], ty = ax[n * 6 + 4], tz = ax[n * 6 + 5];
    const float theta = sqrtf(vx * vx + vy * vy + vz * vz);
    const float kinv = 1.0f / fmaxf(theta, 1e-12f);
    const float kx = vx * kinv, ky = vy * kinv, kz = vz * kinv;
    const float ct = __cosf(theta), st = __sinf(theta);
    const float oc = 1.0f - ct;
    const float r00 = 1.0f + oc * (-(ky * ky + kz * kz));
    const float r01 = -st * kz + oc * kx * ky;
    const float r02 =  st * ky + oc * kx * kz;
    const float r10 =  st * kz + oc * kx * ky;
    const float r11 = 1.0f + oc * (-(kx * kx + kz * kz));
    const float r12 = -st * kx + oc * ky * kz;
    const float r20 = -st * ky + oc * kx * kz;
    const float r21 =  st * kx + oc * ky * kz;
    const float r22 = 1.0f + oc * (-(kx * kx + ky * ky));
    const float px = sampleGrid[n * 3 + 0] + tx;
    const float py = sampleGrid[n * 3 + 1] + ty;
    const float pz = sampleGrid[n * 3 + 2] + tz;
    const float scale = (float)VOL_N / (float)(VOL_N - 1);
    const float icx = (r00 * px + r01 * py + r02 * pz) * scale - 0.5f;
    const float icy = (r10 * px + r11 * py + r12 * pz) * scale - 0.5f;
    const float icz = (r20 * px + r21 * py + r22 * pz) * scale - 0.5f;
    const float hx = (bound[n * 6 + 3] - bound[n * 6 + 0]) * 0.5f;
    const float hy = (bound[n * 6 + 4] - bound[n * 6 + 1]) * 0.5f;
    const float hz = (bound[n * 6 + 5] - bound[n * 6 + 2]) * 0.5f;

    const float m00 = invcov[0], m01 = invcov[1], m02 = invcov[2];
    const float m10 = invcov[3], m11 = invcov[4], m12 = invcov[5];
    const float m20 = invcov[6], m21 = invcov[7], m22 = invcov[8];

    const int pbase = (n * S_PSF + lane) * 3;
    const float ox = xyz_psf[pbase + 0] * hx;
    const float oy = xyz_psf[pbase + 1] * hy;
    const float oz = xyz_psf[pbase + 2] * hz;

    const float ix = fmaf(ox, scale, icx);
    const float iy = fmaf(oy, scale, icy);
    const float iz = fmaf(oz, scale, icz);
    const float x0f = floorf(ix), y0f = floorf(iy), z0f = floorf(iz);
    const float fx = ix - x0f, fy = iy - y0f, fz = iz - z0f;
    const int x0 = (int)x0f, y0 = (int)y0f, z0 = (int)z0f;

    const float wx0 = ((unsigned)x0       < (unsigned)VOL_N) ? (1.0f - fx) : 0.0f;
    const float wx1 = ((unsigned)(x0 + 1) < (unsigned)VOL_N) ? fx          : 0.0f;
    const float wy0 = ((unsigned)y0       < (unsigned)VOL_N) ? (1.0f - fy) : 0.0f;
    const float wy1 = ((unsigned)(y0 + 1) < (unsigned)VOL_N) ? fy          : 0.0f;
    const float wz0 = ((unsigned)z0       < (unsigned)VOL_N) ? (1.0f - fz) : 0.0f;
    const float wz1 = ((unsigned)(z0 + 1) < (unsigned)VOL_N) ? fz          : 0.0f;

    const int xc0 = min(max(x0, 0), VOL_N - 1);
    const int xc1 = min(max(x0 + 1, 0), VOL_N - 1);
    const int yc0 = min(max(y0, 0), VOL_N - 1);
    const int yc1 = min(max(y0 + 1, 0), VOL_N - 1);
    const int zc0 = min(max(z0, 0), VOL_N - 1);
    const int zc1 = min(max(z0 + 1, 0), VOL_N - 1);
    const int zo0 = zc0 << 16, zo1 = zc1 << 16;
    const int yo0 = yc0 << 8, yo1 = yc1 << 8;
    const float v000 = vol[zo0 + yo0 + xc0];
    const float v001 = vol[zo0 + yo0 + xc1];
    const float v010 = vol[zo0 + yo1 + xc0];
    const float v011 = vol[zo0 + yo1 + xc1];
    const float v100 = vol[zo1 + yo0 + xc0];
    const float v101 = vol[zo1 + yo0 + xc1];
    const float v110 = vol[zo1 + yo1 + xc0];
    const float v111 = vol[zo1 + yo1 + xc1];

    const float r0 = fmaf(v001, wx1, v000 * wx0);
    const float r1 = fmaf(v011, wx1, v010 * wx0);
    const float r2 = fmaf(v101, wx1, v100 * wx0);
    const float r3 = fmaf(v111, wx1, v110 * wx0);
    const float s0 = fmaf(r1, wy1, r0 * wy0);
    const float s1 = fmaf(r3, wy1, r2 * wy0);
    const float acc = fmaf(s1, wz1, s0 * wz0);

    const float qx = fmaf(m00, ox, fmaf(m01, oy, m02 * oz));
    const float qy = fmaf(m10, ox, fmaf(m11, oy, m12 * oz));
    const float qz = fmaf(m20, ox, fmaf(m21, oy, m22 * oz));
    const float q = fmaf(ox, qx, fmaf(oy, qy, oz * qz));
    const float w = __expf(-0.5f * q);

    float num = acc * w;
    float den = w;
    #pragma unroll
    for (int m = 32; m >= 1; m >>= 1) {
        num += __shfl_xor(num, m, 64);
        den += __shfl_xor(den, m, 64);
    }
    if (lane == 0) out[n] = num / den;
}

extern "C" void kernel_launch(void* const* d_in, const int* in_sizes, int n_in,
                              void* d_out, int out_size, void* d_ws, size_t ws_size,
                              hipStream_t stream) {
    const float* x        = (const float*)d_in[0];
    const float* sg       = (const float*)d_in[1];
    const float* ax       = (const float*)d_in[2];
    const float* bound    = (const float*)d_in[3];
    const float* invcov   = (const float*)d_in[4];
    const float* xyz_psf  = (const float*)d_in[5];
    float* out            = (float*)d_out;

    const int N = in_sizes[1] / 3;           // sampleGrid is [N][3]
    const size_t sort_bytes = (size_t)(2 * NBUCKET + N) * sizeof(int);
    const size_t sort_pad   = (sort_bytes + 31) & ~(size_t)31;   // align pre to 32B
    const size_t pre_bytes  = (size_t)N * 8 * sizeof(float);

    const bool use_sort = ws_size >= sort_pad + pre_bytes;

    if (use_sort) {
        int* sort_ws = (int*)d_ws;
        float* pre = (float*)((char*)d_ws + sort_pad);
        int* perm = sort_ws + 2 * NBUCKET;

        zero_hist_kernel<<<(NBUCKET + 255) / 256, 256, 0, stream>>>(sort_ws);
        hist_kernel<<<(N + 255) / 256, 256, 0, stream>>>(sg, sort_ws, N);
        scan_kernel<<<1, 1024, 0, stream>>>(sort_ws);
        scatter_kernel<<<(N + 255) / 256, 256, 0, stream>>>(sg, ax, bound, sort_ws, pre, N);

        dim3 block(256);
        dim3 grid((N + 3) / 4);              // 4 samples per block (1/wave)
        psf_sample_vol_kernel<<<grid, block, 0, stream>>>(
            x, invcov, xyz_psf, perm, pre, out, N);
    } else {
        dim3 block(256);
        dim3 grid((N + 3) / 4);
        psf_sample_plain_kernel<<<grid, block, 0, stream>>>(
            x, sg, ax, bound, invcov, xyz_psf, out, N);
    }
}